// Round 7
// baseline (240.887 us; speedup 1.0000x reference)
//
#include <hip/hip_runtime.h>
#include <hip/hip_bf16.h>

typedef unsigned short u16;
typedef unsigned int u32;
typedef __attribute__((ext_vector_type(8))) __bf16 bf16x8;
typedef __attribute__((ext_vector_type(2))) __bf16 bf16x2;
typedef __attribute__((ext_vector_type(4))) float f32x4;
typedef __attribute__((ext_vector_type(4))) short short4v;
typedef __attribute__((ext_vector_type(2))) u32 u32x2;

#define B_ 4
#define T_ 2048
#define C_ 1024
#define NH_ 16
#define HD_ 64

static __device__ __forceinline__ u16 f2bf(float f) {
  u32 u = __builtin_bit_cast(u32, f);
  u32 r = (u + 0x7fffu + ((u >> 16) & 1u)) >> 16;
  return (u16)r;
}

// pack two f32 -> two bf16 in one u32 (a -> low16, b -> high16)
static __device__ __forceinline__ u32 pk_bf16(float a, float b) {
#if __has_builtin(__builtin_amdgcn_cvt_pk_bf16_f32)
  bf16x2 v = __builtin_amdgcn_cvt_pk_bf16_f32(a, b);
  return __builtin_bit_cast(u32, v);
#else
  u32 ua = __builtin_bit_cast(u32, a) + 0x8000u;
  u32 ub = __builtin_bit_cast(u32, b) + 0x8000u;
  return __builtin_amdgcn_perm(ub, ua, 0x07060302u);
#endif
}

static __device__ __forceinline__ float fexp2(float x) {
#if __has_builtin(__builtin_amdgcn_exp2f)
  return __builtin_amdgcn_exp2f(x);
#else
  return exp2f(x);
#endif
}

// async global->LDS, 16B per lane (global_load_lds_dwordx4)
static __device__ __forceinline__ void load_lds16(const u16* g, u16* l) {
  __builtin_amdgcn_global_load_lds(
      (const __attribute__((address_space(1))) u32*)g,
      (__attribute__((address_space(3))) u32*)l, 16, 0, 0);
}

// Hardened barrier: ISA-level full drain (vmcnt/expcnt/lgkmcnt = 0) pinned
// with sched_barrier so no LDS/VMEM op can be scheduled across it.
static __device__ __forceinline__ void barrier_full_drain() {
  __builtin_amdgcn_sched_barrier(0);
#if __has_builtin(__builtin_amdgcn_s_waitcnt)
  __builtin_amdgcn_s_waitcnt(0);  // vmcnt(0) expcnt(0) lgkmcnt(0)
#else
  asm volatile("s_waitcnt vmcnt(0) lgkmcnt(0)" ::: "memory");
#endif
  __builtin_amdgcn_sched_barrier(0);
  __syncthreads();
  __builtin_amdgcn_sched_barrier(0);
}

static __device__ __forceinline__ f32x4 mfma32(bf16x8 a, bf16x8 b, f32x4 c) {
  return __builtin_amdgcn_mfma_f32_16x16x32_bf16(a, b, c, 0, 0, 0);
}

// 16x16x16 bf16 MFMA (K=16, k = quad*4+r)
static __device__ __forceinline__ f32x4 mfma16(short4v a, short4v b, f32x4 c) {
#if __has_builtin(__builtin_amdgcn_mfma_f32_16x16x16bf16_1k)
  return __builtin_amdgcn_mfma_f32_16x16x16bf16_1k(a, b, c, 0, 0, 0);
#else
  asm volatile("v_mfma_f32_16x16x16_bf16 %0, %1, %2, %0\n\t"
               "s_nop 7\n\ts_nop 7"
               : "+v"(c)
               : "v"(a), "v"(b));
  return c;
#endif
}

// ---------------- fused prep: cast x + transpose-cast both weights ----------
__global__ __launch_bounds__(256) void prep(const float* __restrict__ x,
                                            const float* __restrict__ wqkv,
                                            const float* __restrict__ wproj,
                                            u16* __restrict__ x_bf,
                                            u16* __restrict__ wqkvT,
                                            u16* __restrict__ wprojT) {
  __shared__ float tile[32][33];
  const int bid = blockIdx.x, tid = threadIdx.x;
  if (bid < 4096) {  // cast x -> bf16
    int i = (bid * 256 + tid) * 8;
    float4 a = *(const float4*)(x + i);
    float4 b = *(const float4*)(x + i + 4);
    u16 r[8] = {f2bf(a.x), f2bf(a.y), f2bf(a.z), f2bf(a.w),
                f2bf(b.x), f2bf(b.y), f2bf(b.z), f2bf(b.w)};
    *(uint4*)(x_bf + i) = *(const uint4*)r;
    return;
  }
  const float* in;
  u16* out;
  int K = 1024, N, bx, by;
  if (bid < 4096 + 3072) {
    int id = bid - 4096;
    in = wqkv; out = wqkvT; N = 3072;
    bx = (id % 96) * 32; by = (id / 96) * 32;
  } else {
    int id = bid - 7168;
    in = wproj; out = wprojT; N = 1024;
    bx = (id % 32) * 32; by = (id / 32) * 32;
  }
  int tx = tid & 31, ty = tid >> 5;
  for (int r = ty; r < 32; r += 8)
    tile[r][tx] = in[(size_t)(by + r) * N + bx + tx];
  __syncthreads();
  for (int r = ty; r < 32; r += 8)
    out[(size_t)(bx + r) * K + by + tx] = f2bf(tile[tx][r]);
}

// ---------------- QKV GEMM, 2-phase double-buffered (proven engine) --------
// A[8192][1024] * Bt[3072][1024]^T. Q,K cols (c<2048) -> qk[8192][2048]
// (Q scaled by qscale) via LDS-assembled row-major 16B-line stores. V cols
// -> vt[(b*16+h)*64+d][2048] with per-64-tile permute via LDS transpose.
__global__ __launch_bounds__(256) void gemm_qkv(const u16* __restrict__ A,
                                                const u16* __restrict__ Bt,
                                                u16* __restrict__ qk,
                                                u16* __restrict__ vt,
                                                float qscale) {
  const int K_ = 1024;
  __shared__ __align__(16) u16 smem[32768];  // As[2](16K u16) Bs[2](16K u16)
  u16* const Asb = smem;
  u16* const Bsb = smem + 16384;
  const int tid = threadIdx.x;
  const int wave = tid >> 6, lane = tid & 63;
  const int wm = (wave >> 1) * 64, wn = (wave & 1) * 64;
  const int m0 = blockIdx.x * 128, n0 = blockIdx.y * 128;
  const int col = lane & 15, quad = lane >> 4;
  const int lcol = (lane & 7) * 8;
  const int sg = ((lane & 7) ^ ((lane >> 3) & 7)) * 8;
  const int ag = ((quad ^ (col & 7)) * 8);

  f32x4 acc[4][4] = {};

  // advancing staging pointers (strength-reduced addressing)
  const u16* pa[4];
  const u16* pb[4];
  u16* da[4];
  u16* db[4];
  for (int i = 0; i < 4; i++) {
    int row = (wave * 4 + i) * 8 + (lane >> 3);
    pa[i] = A + (size_t)(m0 + row) * K_ + sg;
    pb[i] = Bt + (size_t)(n0 + row) * K_ + sg;
    da[i] = Asb + row * 64 + lcol;
    db[i] = Bsb + row * 64 + lcol;
  }

  auto stage = [&](int buf) {
    const int bo = buf * 8192;
    for (int i = 0; i < 4; i++) {
      load_lds16(pa[i], da[i] + bo);
      load_lds16(pb[i], db[i] + bo);
      pa[i] += 64;
      pb[i] += 64;
    }
  };

  stage(0);
  __syncthreads();  // drains vmcnt(0): buf0 landed
  int cur = 0;
  for (int kt = 0; kt < K_; kt += 64) {
    if (kt + 64 < K_) stage(cur ^ 1);  // issue next tile's loads first
    const u16* As = Asb + cur * 8192;
    const u16* Bs = Bsb + cur * 8192;
    for (int ks = 0; ks < 64; ks += 32) {
      const int o = ag ^ ks;
      bf16x8 af[4], bfr[4];
      for (int t = 0; t < 4; t++) {
        af[t]  = *(const bf16x8*)(&As[(wm + t * 16 + col) * 64 + o]);
        bfr[t] = *(const bf16x8*)(&Bs[(wn + t * 16 + col) * 64 + o]);
      }
      __builtin_amdgcn_s_setprio(1);
      for (int i = 0; i < 4; i++)
        for (int j = 0; j < 4; j++)
          acc[i][j] = mfma32(af[i], bfr[j], acc[i][j]);
      __builtin_amdgcn_s_setprio(0);
    }
    __syncthreads();  // drains stage(cur^1) vmcnt + all LDS reads of buf cur
    cur ^= 1;
  }

  if (n0 < 2048) {
    // Q/K epilogue v2: assemble the 128x128 tile row-major in LDS (stride
    // 136 u16 = 272 B: 16B-aligned rows for ds_read_b128, quad rows land 16
    // banks apart), then write full 16B lines. Replaces 16 scalar u16
    // global stores/lane (partial-line write-allocate RMW, ~27 MB extra
    // FETCH) with 8 uint4 stores/thread. smem free after final barrier.
    const float sc = (n0 < 1024) ? qscale : 1.0f;  // block-uniform
    for (int i = 0; i < 4; i++)
      for (int j = 0; j < 4; j++) {
        int rl = wm + i * 16 + quad * 4;
        int cl = wn + j * 16 + col;
        for (int reg = 0; reg < 4; reg++)
          smem[(rl + reg) * 136 + cl] = f2bf(acc[i][j][reg] * sc);
      }
    __syncthreads();
    {
      int row = tid >> 1, half = tid & 1;
      const u16* src = &smem[row * 136 + half * 64];
      u16* dst = qk + (size_t)(m0 + row) * 2048 + n0 + half * 64;
      for (int k = 0; k < 8; k++)
        *(uint4*)(dst + k * 8) = *(const uint4*)(src + k * 8);
    }
    return;
  }

  // V epilogue: transpose via LDS. S[c_local][p], p = wm + reg + i*4 + quad*16
  // smem (64 KiB) is free after the loop's final barrier; need 34 KiB.
  for (int i = 0; i < 4; i++)
    for (int j = 0; j < 4; j++) {
      int cl = wn + j * 16 + col;
      u16 tmp[4] __attribute__((aligned(8)));
      for (int reg = 0; reg < 4; reg++) tmp[reg] = f2bf(acc[i][j][reg]);
      *(unsigned long long*)(&smem[cl * 136 + wm + i * 4 + quad * 16]) =
          *(const unsigned long long*)tmp;
    }
  __syncthreads();
  {
    int cl = tid >> 1, half = tid & 1;
    int cv = (n0 - 2048) + cl, hh = cv >> 6, d = cv & 63;
    int b = m0 >> 11;
    u16* dst = vt + ((size_t)((b << 4) + hh) * 64 + d) * 2048 + (m0 & 2047) + half * 64;
    const u16* src = &smem[cl * 136 + half * 64];
    for (int ii = 0; ii < 8; ii++)
      *(uint4*)(dst + ii * 8) = *(const uint4*)(src + ii * 8);
  }
}

// ---------------- proj GEMM, 2-phase double-buffered ----------------------
__global__ __launch_bounds__(256) void gemm_proj(const u16* __restrict__ A,
                                                 const u16* __restrict__ Bt,
                                                 float* __restrict__ C,
                                                 int M, int N, int K) {
  __shared__ __align__(16) u16 smem[32768];
  u16* const Asb = smem;
  u16* const Bsb = smem + 16384;
  const int tid = threadIdx.x;
  const int wave = tid >> 6, lane = tid & 63;
  const int wm = (wave >> 1) * 64, wn = (wave & 1) * 64;
  const int m0 = blockIdx.x * 128, n0 = blockIdx.y * 128;
  const int col = lane & 15, quad = lane >> 4;
  const int lcol = (lane & 7) * 8;
  const int sg = ((lane & 7) ^ ((lane >> 3) & 7)) * 8;
  const int ag = ((quad ^ (col & 7)) * 8);

  f32x4 acc[4][4] = {};

  const u16* pa[4];
  const u16* pb[4];
  u16* da[4];
  u16* db[4];
  for (int i = 0; i < 4; i++) {
    int row = (wave * 4 + i) * 8 + (lane >> 3);
    pa[i] = A + (size_t)(m0 + row) * K + sg;
    pb[i] = Bt + (size_t)(n0 + row) * K + sg;
    da[i] = Asb + row * 64 + lcol;
    db[i] = Bsb + row * 64 + lcol;
  }

  auto stage = [&](int buf) {
    const int bo = buf * 8192;
    for (int i = 0; i < 4; i++) {
      load_lds16(pa[i], da[i] + bo);
      load_lds16(pb[i], db[i] + bo);
      pa[i] += 64;
      pb[i] += 64;
    }
  };

  stage(0);
  __syncthreads();
  int cur = 0;
  for (int kt = 0; kt < K; kt += 64) {
    if (kt + 64 < K) stage(cur ^ 1);
    const u16* As = Asb + cur * 8192;
    const u16* Bs = Bsb + cur * 8192;
    for (int ks = 0; ks < 64; ks += 32) {
      const int o = ag ^ ks;
      bf16x8 af[4], bfr[4];
      for (int t = 0; t < 4; t++) {
        af[t]  = *(const bf16x8*)(&As[(wm + t * 16 + col) * 64 + o]);
        bfr[t] = *(const bf16x8*)(&Bs[(wn + t * 16 + col) * 64 + o]);
      }
      __builtin_amdgcn_s_setprio(1);
      for (int i = 0; i < 4; i++)
        for (int j = 0; j < 4; j++)
          acc[i][j] = mfma32(af[i], bfr[j], acc[i][j]);
      __builtin_amdgcn_s_setprio(0);
    }
    __syncthreads();
    cur ^= 1;
  }

  for (int i = 0; i < 4; i++)
    for (int j = 0; j < 4; j++) {
      int r = m0 + wm + i * 16 + quad * 4;
      int c = n0 + wn + j * 16 + col;
      for (int reg = 0; reg < 4; reg++)
        C[(size_t)(r + reg) * N + c] = acc[i][j][reg];
    }
}

// ---------------- fused causal flash attention v8 (proven 58.7 us) ---------
// qk[8192][2048] (Q scaled | K), vt[(bh)*64+d][2048] pre-permuted.
// ONE q-tile per block, grid 2048 = 32 qi x 64 bh, longest-first; 5 blocks/CU.
__global__ __launch_bounds__(256, 5) void attn_fused(const u16* __restrict__ qk,
                                                     const u16* __restrict__ vt,
                                                     u16* __restrict__ o) {
  const int qi = 31 - (blockIdx.x >> 6);  // longest blocks first
  const int bh = blockIdx.x & 63, b = bh >> 4, h = bh & 15;
  const int tid = threadIdx.x, wave = tid >> 6, lane = tid & 63;
  const int col = lane & 15, quad = lane >> 4;

  const int jtmax = qi;

  __shared__ __align__(16) u16 Ks[2][4096];
  __shared__ __align__(16) u16 Vs[2][4096];

  const u16* qkb = qk + (size_t)b * 2048 * 2048;
  const u16* vtb = vt + (size_t)bh * 64 * 2048;

  // Q fragments (B-operand of S^T = K * Q^T), pre-scaled by 0.125*log2(e)
  bf16x8 qf[2];
  {
    int q = qi * 64 + wave * 16 + col;
    const u16* qp = qkb + (size_t)q * 2048 + h * 64;
    qf[0] = *(const bf16x8*)(qp + quad * 8);
    qf[1] = *(const bf16x8*)(qp + 32 + quad * 8);
  }

  f32x4 lacc = {};
  f32x4 Oacc[4] = {};

  const int sg  = ((lane & 7) ^ ((lane >> 3) & 7)) * 8;
  const int swq = col & 7;
  const int kg0 = (quad ^ swq) * 8;        // K frag granule (k1 = kg0^32)
  const int vg0 = ((2 * quad) ^ swq) * 8;  // V frag granule (v1 = vg0^8)

  // staging pointers, advanced per tile (strength-reduced addressing)
  const int r0 = wave * 8 + (lane >> 3);       // rows 0..31
  const int r1 = r0 + 32;
  const u16* kp0 = qkb + (size_t)r0 * 2048 + 1024 + h * 64 + sg;
  const u16* kp1 = qkb + (size_t)r1 * 2048 + 1024 + h * 64 + sg;
  const u16* vp0 = vtb + (size_t)r0 * 2048 + sg;
  const u16* vp1 = vtb + (size_t)r1 * 2048 + sg;
  u16* kd0 = &Ks[0][(wave * 64 + lane) * 8];
  u16* kd1 = kd0 + 2048;
  u16* vd0 = &Vs[0][(wave * 64 + lane) * 8];
  u16* vd1 = vd0 + 2048;

  auto stage = [&](int buf) {
    int bo = buf * 4096;
    load_lds16(kp0, kd0 + bo);
    load_lds16(kp1, kd1 + bo);
    load_lds16(vp0, vd0 + bo);
    load_lds16(vp1, vd1 + bo);
    kp0 += 64 * 2048; kp1 += 64 * 2048;  // next 64 K rows
    vp0 += 64; vp1 += 64;                // next 64 V cols
  };

  stage(0);
  for (int jt = 0; jt <= jtmax; jt++) {
    const int cur = jt & 1;
    barrier_full_drain();  // LDS-DMA of stage(jt) landed; prior reads done
    if (jt < jtmax) stage(cur ^ 1);

    const u16* K_ = Ks[cur];
    const u16* V_ = Vs[cur];

    f32x4 s[4] = {};
    for (int nt = 0; nt < 4; nt++) {
      bf16x8 k0 = *(const bf16x8*)(K_ + (nt * 16 + col) * 64 + kg0);
      bf16x8 k1 = *(const bf16x8*)(K_ + (nt * 16 + col) * 64 + (kg0 ^ 32));
      s[nt] = mfma32(k0, qf[0], s[nt]);
      s[nt] = mfma32(k1, qf[1], s[nt]);
    }

    if (jt == jtmax) {  // diagonal tile: causal mask
      for (int nt = 0; nt < 4; nt++)
        for (int r = 0; r < 4; r++) {
          int j = nt * 16 + quad * 4 + r, q = wave * 16 + col;
          if (j > q) s[nt][r] = -INFINITY;
        }
    }

    // p = exp2(s); accumulate private l; pack bf16 P-fragments.
    u32 pb[8];
    {
      f32x4 ps = {};
      for (int nt = 0; nt < 4; nt++) {
        f32x4 p;
        for (int r = 0; r < 4; r++) p[r] = fexp2(s[nt][r]);
        ps += p;
        pb[nt * 2]     = pk_bf16(p[0], p[1]);
        pb[nt * 2 + 1] = pk_bf16(p[2], p[3]);
      }
      lacc += ps;
    }

    for (int dt = 0; dt < 4; dt++) {
      uint4 vb0 = *(const uint4*)(V_ + (dt * 16 + col) * 64 + vg0);
      uint4 vb1 = *(const uint4*)(V_ + (dt * 16 + col) * 64 + (vg0 ^ 8));
      short4v vf[4];
      vf[0] = __builtin_bit_cast(short4v, (u32x2){vb0.x, vb0.y});
      vf[1] = __builtin_bit_cast(short4v, (u32x2){vb0.z, vb0.w});
      vf[2] = __builtin_bit_cast(short4v, (u32x2){vb1.x, vb1.y});
      vf[3] = __builtin_bit_cast(short4v, (u32x2){vb1.z, vb1.w});
      for (int nt = 0; nt < 4; nt++) {
        short4v pf = __builtin_bit_cast(short4v, (u32x2){pb[nt * 2], pb[nt * 2 + 1]});
        Oacc[dt] = mfma16(vf[nt], pf, Oacc[dt]);
      }
    }
  }

  {
    float l = (lacc[0] + lacc[1]) + (lacc[2] + lacc[3]);
    l += __shfl_xor(l, 16, 64);
    l += __shfl_xor(l, 32, 64);
    float rl = 1.0f / l;
    int q = qi * 64 + wave * 16 + col;
    u16* op = o + (size_t)(b * 2048 + q) * 1024 + h * 64;
    for (int dt = 0; dt < 4; dt++) {
      u16 ob[4] __attribute__((aligned(8)));
      for (int r = 0; r < 4; r++) ob[r] = f2bf(Oacc[dt][r] * rl);
      *(uint2*)(op + dt * 16 + quad * 4) = *(const uint2*)ob;
    }
  }
}

extern "C" void kernel_launch(void* const* d_in, const int* in_sizes, int n_in,
                              void* d_out, int out_size, void* d_ws, size_t ws_size,
                              hipStream_t stream) {
  const float* x      = (const float*)d_in[0];  // [B,T,C]
  const float* w_qkv  = (const float*)d_in[1];  // [C, 3C]
  const float* w_proj = (const float*)d_in[2];  // [C, C]
  float* out = (float*)d_out;

  u16* x_bf    = (u16*)d_ws;                    // 8192*1024
  u16* wqkvT   = x_bf + (size_t)8192 * 1024;    // 3072*1024
  u16* wprojT  = wqkvT + (size_t)3072 * 1024;   // 1024*1024
  u16* qk_buf  = wprojT + (size_t)1024 * 1024;  // 8192*2048  (Qscaled | K)
  u16* vt_perm = qk_buf + (size_t)8192 * 2048;  // 64*64*2048
  u16* attn_bf = vt_perm + (size_t)64 * 64 * 2048;  // 8192*1024

  const float qscale = 0.125f * 1.44269504f;    // 1/sqrt(64) * log2(e)

  prep<<<8192, 256, 0, stream>>>(x, w_qkv, w_proj, x_bf, wqkvT, wprojT);

  gemm_qkv<<<dim3(64, 24), 256, 0, stream>>>(x_bf, wqkvT, qk_buf, vt_perm, qscale);

  attn_fused<<<2048, 256, 0, stream>>>(qk_buf, vt_perm, attn_bf);

  gemm_proj<<<dim3(64, 8), 256, 0, stream>>>(attn_bf, wprojT, out, 8192, 1024, 1024);
}

// Round 8
// 215.831 us; speedup vs baseline: 1.1161x; 1.1161x over previous
//
#include <hip/hip_runtime.h>
#include <hip/hip_bf16.h>

typedef unsigned short u16;
typedef unsigned int u32;
typedef __attribute__((ext_vector_type(8))) __bf16 bf16x8;
typedef __attribute__((ext_vector_type(2))) __bf16 bf16x2;
typedef __attribute__((ext_vector_type(4))) float f32x4;
typedef __attribute__((ext_vector_type(4))) short short4v;
typedef __attribute__((ext_vector_type(2))) u32 u32x2;

#define B_ 4
#define T_ 2048
#define C_ 1024
#define NH_ 16
#define HD_ 64

static __device__ __forceinline__ u16 f2bf(float f) {
  u32 u = __builtin_bit_cast(u32, f);
  u32 r = (u + 0x7fffu + ((u >> 16) & 1u)) >> 16;
  return (u16)r;
}

// pack two f32 -> two bf16 in one u32 (a -> low16, b -> high16)
static __device__ __forceinline__ u32 pk_bf16(float a, float b) {
#if __has_builtin(__builtin_amdgcn_cvt_pk_bf16_f32)
  bf16x2 v = __builtin_amdgcn_cvt_pk_bf16_f32(a, b);
  return __builtin_bit_cast(u32, v);
#else
  u32 ua = __builtin_bit_cast(u32, a) + 0x8000u;
  u32 ub = __builtin_bit_cast(u32, b) + 0x8000u;
  return __builtin_amdgcn_perm(ub, ua, 0x07060302u);
#endif
}

static __device__ __forceinline__ float fexp2(float x) {
#if __has_builtin(__builtin_amdgcn_exp2f)
  return __builtin_amdgcn_exp2f(x);
#else
  return exp2f(x);
#endif
}

// async global->LDS, 16B per lane (global_load_lds_dwordx4)
static __device__ __forceinline__ void load_lds16(const u16* g, u16* l) {
  __builtin_amdgcn_global_load_lds(
      (const __attribute__((address_space(1))) u32*)g,
      (__attribute__((address_space(3))) u32*)l, 16, 0, 0);
}

// Hardened barrier: ISA-level full drain (vmcnt/expcnt/lgkmcnt = 0) pinned
// with sched_barrier so no LDS/VMEM op can be scheduled across it.
static __device__ __forceinline__ void barrier_full_drain() {
  __builtin_amdgcn_sched_barrier(0);
#if __has_builtin(__builtin_amdgcn_s_waitcnt)
  __builtin_amdgcn_s_waitcnt(0);  // vmcnt(0) expcnt(0) lgkmcnt(0)
#else
  asm volatile("s_waitcnt vmcnt(0) lgkmcnt(0)" ::: "memory");
#endif
  __builtin_amdgcn_sched_barrier(0);
  __syncthreads();
  __builtin_amdgcn_sched_barrier(0);
}

static __device__ __forceinline__ f32x4 mfma32(bf16x8 a, bf16x8 b, f32x4 c) {
  return __builtin_amdgcn_mfma_f32_16x16x32_bf16(a, b, c, 0, 0, 0);
}

// 16x16x16 bf16 MFMA (K=16, k = quad*4+r)
static __device__ __forceinline__ f32x4 mfma16(short4v a, short4v b, f32x4 c) {
#if __has_builtin(__builtin_amdgcn_mfma_f32_16x16x16bf16_1k)
  return __builtin_amdgcn_mfma_f32_16x16x16bf16_1k(a, b, c, 0, 0, 0);
#else
  asm volatile("v_mfma_f32_16x16x16_bf16 %0, %1, %2, %0\n\t"
               "s_nop 7\n\ts_nop 7"
               : "+v"(c)
               : "v"(a), "v"(b));
  return c;
#endif
}

// ---------------- fused prep: cast x + transpose-cast both weights ----------
__global__ __launch_bounds__(256) void prep(const float* __restrict__ x,
                                            const float* __restrict__ wqkv,
                                            const float* __restrict__ wproj,
                                            u16* __restrict__ x_bf,
                                            u16* __restrict__ wqkvT,
                                            u16* __restrict__ wprojT) {
  __shared__ float tile[32][33];
  const int bid = blockIdx.x, tid = threadIdx.x;
  if (bid < 4096) {  // cast x -> bf16
    int i = (bid * 256 + tid) * 8;
    float4 a = *(const float4*)(x + i);
    float4 b = *(const float4*)(x + i + 4);
    u16 r[8] = {f2bf(a.x), f2bf(a.y), f2bf(a.z), f2bf(a.w),
                f2bf(b.x), f2bf(b.y), f2bf(b.z), f2bf(b.w)};
    *(uint4*)(x_bf + i) = *(const uint4*)r;
    return;
  }
  const float* in;
  u16* out;
  int K = 1024, N, bx, by;
  if (bid < 4096 + 3072) {
    int id = bid - 4096;
    in = wqkv; out = wqkvT; N = 3072;
    bx = (id % 96) * 32; by = (id / 96) * 32;
  } else {
    int id = bid - 7168;
    in = wproj; out = wprojT; N = 1024;
    bx = (id % 32) * 32; by = (id / 32) * 32;
  }
  int tx = tid & 31, ty = tid >> 5;
  for (int r = ty; r < 32; r += 8)
    tile[r][tx] = in[(size_t)(by + r) * N + bx + tx];
  __syncthreads();
  for (int r = ty; r < 32; r += 8)
    out[(size_t)(bx + r) * K + by + tx] = f2bf(tile[tx][r]);
}

// ---------------- QKV GEMM, 2-phase double-buffered (proven 58.7 us) -------
// A[8192][1024] * Bt[3072][1024]^T. Q,K cols (c<2048) -> qk[8192][2048]
// (Q scaled by qscale). V cols -> vt[(b*16+h)*64+d][2048] with per-64-tile
// permute g(tl)=reg|(i<<2)|(quad<<4) via an LDS transpose (pad 136).
__global__ __launch_bounds__(256) void gemm_qkv(const u16* __restrict__ A,
                                                const u16* __restrict__ Bt,
                                                u16* __restrict__ qk,
                                                u16* __restrict__ vt,
                                                float qscale) {
  const int K_ = 1024;
  __shared__ __align__(16) u16 smem[32768];  // As[2](16K u16) Bs[2](16K u16)
  u16* const Asb = smem;
  u16* const Bsb = smem + 16384;
  const int tid = threadIdx.x;
  const int wave = tid >> 6, lane = tid & 63;
  const int wm = (wave >> 1) * 64, wn = (wave & 1) * 64;
  const int m0 = blockIdx.x * 128, n0 = blockIdx.y * 128;
  const int col = lane & 15, quad = lane >> 4;
  const int lcol = (lane & 7) * 8;
  const int sg = ((lane & 7) ^ ((lane >> 3) & 7)) * 8;
  const int ag = ((quad ^ (col & 7)) * 8);

  f32x4 acc[4][4] = {};

  // advancing staging pointers (strength-reduced addressing)
  const u16* pa[4];
  const u16* pb[4];
  u16* da[4];
  u16* db[4];
  for (int i = 0; i < 4; i++) {
    int row = (wave * 4 + i) * 8 + (lane >> 3);
    pa[i] = A + (size_t)(m0 + row) * K_ + sg;
    pb[i] = Bt + (size_t)(n0 + row) * K_ + sg;
    da[i] = Asb + row * 64 + lcol;
    db[i] = Bsb + row * 64 + lcol;
  }

  auto stage = [&](int buf) {
    const int bo = buf * 8192;
    for (int i = 0; i < 4; i++) {
      load_lds16(pa[i], da[i] + bo);
      load_lds16(pb[i], db[i] + bo);
      pa[i] += 64;
      pb[i] += 64;
    }
  };

  stage(0);
  __syncthreads();  // drains vmcnt(0): buf0 landed
  int cur = 0;
  for (int kt = 0; kt < K_; kt += 64) {
    if (kt + 64 < K_) stage(cur ^ 1);  // issue next tile's loads first
    const u16* As = Asb + cur * 8192;
    const u16* Bs = Bsb + cur * 8192;
    for (int ks = 0; ks < 64; ks += 32) {
      const int o = ag ^ ks;
      bf16x8 af[4], bfr[4];
      for (int t = 0; t < 4; t++) {
        af[t]  = *(const bf16x8*)(&As[(wm + t * 16 + col) * 64 + o]);
        bfr[t] = *(const bf16x8*)(&Bs[(wn + t * 16 + col) * 64 + o]);
      }
      __builtin_amdgcn_s_setprio(1);
      for (int i = 0; i < 4; i++)
        for (int j = 0; j < 4; j++)
          acc[i][j] = mfma32(af[i], bfr[j], acc[i][j]);
      __builtin_amdgcn_s_setprio(0);
    }
    __syncthreads();  // drains stage(cur^1) vmcnt + all LDS reads of buf cur
    cur ^= 1;
  }

  if (n0 < 2048) {  // Q/K epilogue -> qk[r][c], stride 2048
    for (int i = 0; i < 4; i++)
      for (int j = 0; j < 4; j++) {
        int r = m0 + wm + i * 16 + quad * 4;
        int c = n0 + wn + j * 16 + col;
        float sc = (c < 1024) ? qscale : 1.0f;
        for (int reg = 0; reg < 4; reg++)
          qk[(size_t)(r + reg) * 2048 + c] = f2bf(acc[i][j][reg] * sc);
      }
    return;
  }

  // V epilogue: transpose via LDS. S[c_local][p], p = wm + reg + i*4 + quad*16
  // smem (64 KiB) is free after the loop's final barrier; need 34 KiB.
  for (int i = 0; i < 4; i++)
    for (int j = 0; j < 4; j++) {
      int cl = wn + j * 16 + col;
      u16 tmp[4] __attribute__((aligned(8)));
      for (int reg = 0; reg < 4; reg++) tmp[reg] = f2bf(acc[i][j][reg]);
      *(unsigned long long*)(&smem[cl * 136 + wm + i * 4 + quad * 16]) =
          *(const unsigned long long*)tmp;
    }
  __syncthreads();
  {
    int cl = tid >> 1, half = tid & 1;
    int cv = (n0 - 2048) + cl, hh = cv >> 6, d = cv & 63;
    int b = m0 >> 11;
    u16* dst = vt + ((size_t)((b << 4) + hh) * 64 + d) * 2048 + (m0 & 2047) + half * 64;
    const u16* src = &smem[cl * 136 + half * 64];
    for (int ii = 0; ii < 8; ii++)
      *(uint4*)(dst + ii * 8) = *(const uint4*)(src + ii * 8);
  }
}

// ---------------- proj GEMM, 2-phase double-buffered ----------------------
__global__ __launch_bounds__(256) void gemm_proj(const u16* __restrict__ A,
                                                 const u16* __restrict__ Bt,
                                                 float* __restrict__ C,
                                                 int M, int N, int K) {
  __shared__ __align__(16) u16 smem[32768];
  u16* const Asb = smem;
  u16* const Bsb = smem + 16384;
  const int tid = threadIdx.x;
  const int wave = tid >> 6, lane = tid & 63;
  const int wm = (wave >> 1) * 64, wn = (wave & 1) * 64;
  const int m0 = blockIdx.x * 128, n0 = blockIdx.y * 128;
  const int col = lane & 15, quad = lane >> 4;
  const int lcol = (lane & 7) * 8;
  const int sg = ((lane & 7) ^ ((lane >> 3) & 7)) * 8;
  const int ag = ((quad ^ (col & 7)) * 8);

  f32x4 acc[4][4] = {};

  const u16* pa[4];
  const u16* pb[4];
  u16* da[4];
  u16* db[4];
  for (int i = 0; i < 4; i++) {
    int row = (wave * 4 + i) * 8 + (lane >> 3);
    pa[i] = A + (size_t)(m0 + row) * K + sg;
    pb[i] = Bt + (size_t)(n0 + row) * K + sg;
    da[i] = Asb + row * 64 + lcol;
    db[i] = Bsb + row * 64 + lcol;
  }

  auto stage = [&](int buf) {
    const int bo = buf * 8192;
    for (int i = 0; i < 4; i++) {
      load_lds16(pa[i], da[i] + bo);
      load_lds16(pb[i], db[i] + bo);
      pa[i] += 64;
      pb[i] += 64;
    }
  };

  stage(0);
  __syncthreads();
  int cur = 0;
  for (int kt = 0; kt < K; kt += 64) {
    if (kt + 64 < K) stage(cur ^ 1);
    const u16* As = Asb + cur * 8192;
    const u16* Bs = Bsb + cur * 8192;
    for (int ks = 0; ks < 64; ks += 32) {
      const int o = ag ^ ks;
      bf16x8 af[4], bfr[4];
      for (int t = 0; t < 4; t++) {
        af[t]  = *(const bf16x8*)(&As[(wm + t * 16 + col) * 64 + o]);
        bfr[t] = *(const bf16x8*)(&Bs[(wn + t * 16 + col) * 64 + o]);
      }
      __builtin_amdgcn_s_setprio(1);
      for (int i = 0; i < 4; i++)
        for (int j = 0; j < 4; j++)
          acc[i][j] = mfma32(af[i], bfr[j], acc[i][j]);
      __builtin_amdgcn_s_setprio(0);
    }
    __syncthreads();
    cur ^= 1;
  }

  for (int i = 0; i < 4; i++)
    for (int j = 0; j < 4; j++) {
      int r = m0 + wm + i * 16 + quad * 4;
      int c = n0 + wn + j * 16 + col;
      for (int reg = 0; reg < 4; reg++)
        C[(size_t)(r + reg) * N + c] = acc[i][j][reg];
    }
}

// ---------------- fused causal flash attention v8 (proven 58.7 us) ---------
// qk[8192][2048] (Q scaled | K), vt[(bh)*64+d][2048] pre-permuted.
// ONE q-tile per block, grid 2048 = 32 qi x 64 bh, longest-first; 5 blocks/CU.
__global__ __launch_bounds__(256, 5) void attn_fused(const u16* __restrict__ qk,
                                                     const u16* __restrict__ vt,
                                                     u16* __restrict__ o) {
  const int qi = 31 - (blockIdx.x >> 6);  // longest blocks first
  const int bh = blockIdx.x & 63, b = bh >> 4, h = bh & 15;
  const int tid = threadIdx.x, wave = tid >> 6, lane = tid & 63;
  const int col = lane & 15, quad = lane >> 4;

  const int jtmax = qi;

  __shared__ __align__(16) u16 Ks[2][4096];
  __shared__ __align__(16) u16 Vs[2][4096];

  const u16* qkb = qk + (size_t)b * 2048 * 2048;
  const u16* vtb = vt + (size_t)bh * 64 * 2048;

  // Q fragments (B-operand of S^T = K * Q^T), pre-scaled by 0.125*log2(e)
  bf16x8 qf[2];
  {
    int q = qi * 64 + wave * 16 + col;
    const u16* qp = qkb + (size_t)q * 2048 + h * 64;
    qf[0] = *(const bf16x8*)(qp + quad * 8);
    qf[1] = *(const bf16x8*)(qp + 32 + quad * 8);
  }

  f32x4 lacc = {};
  f32x4 Oacc[4] = {};

  const int sg  = ((lane & 7) ^ ((lane >> 3) & 7)) * 8;
  const int swq = col & 7;
  const int kg0 = (quad ^ swq) * 8;        // K frag granule (k1 = kg0^32)
  const int vg0 = ((2 * quad) ^ swq) * 8;  // V frag granule (v1 = vg0^8)

  // staging pointers, advanced per tile (strength-reduced addressing)
  const int r0 = wave * 8 + (lane >> 3);       // rows 0..31
  const int r1 = r0 + 32;
  const u16* kp0 = qkb + (size_t)r0 * 2048 + 1024 + h * 64 + sg;
  const u16* kp1 = qkb + (size_t)r1 * 2048 + 1024 + h * 64 + sg;
  const u16* vp0 = vtb + (size_t)r0 * 2048 + sg;
  const u16* vp1 = vtb + (size_t)r1 * 2048 + sg;
  u16* kd0 = &Ks[0][(wave * 64 + lane) * 8];
  u16* kd1 = kd0 + 2048;
  u16* vd0 = &Vs[0][(wave * 64 + lane) * 8];
  u16* vd1 = vd0 + 2048;

  auto stage = [&](int buf) {
    int bo = buf * 4096;
    load_lds16(kp0, kd0 + bo);
    load_lds16(kp1, kd1 + bo);
    load_lds16(vp0, vd0 + bo);
    load_lds16(vp1, vd1 + bo);
    kp0 += 64 * 2048; kp1 += 64 * 2048;  // next 64 K rows
    vp0 += 64; vp1 += 64;                // next 64 V cols
  };

  stage(0);
  for (int jt = 0; jt <= jtmax; jt++) {
    const int cur = jt & 1;
    barrier_full_drain();  // LDS-DMA of stage(jt) landed; prior reads done
    if (jt < jtmax) stage(cur ^ 1);

    const u16* K_ = Ks[cur];
    const u16* V_ = Vs[cur];

    f32x4 s[4] = {};
    for (int nt = 0; nt < 4; nt++) {
      bf16x8 k0 = *(const bf16x8*)(K_ + (nt * 16 + col) * 64 + kg0);
      bf16x8 k1 = *(const bf16x8*)(K_ + (nt * 16 + col) * 64 + (kg0 ^ 32));
      s[nt] = mfma32(k0, qf[0], s[nt]);
      s[nt] = mfma32(k1, qf[1], s[nt]);
    }

    if (jt == jtmax) {  // diagonal tile: causal mask
      for (int nt = 0; nt < 4; nt++)
        for (int r = 0; r < 4; r++) {
          int j = nt * 16 + quad * 4 + r, q = wave * 16 + col;
          if (j > q) s[nt][r] = -INFINITY;
        }
    }

    // p = exp2(s); accumulate private l; pack bf16 P-fragments.
    u32 pb[8];
    {
      f32x4 ps = {};
      for (int nt = 0; nt < 4; nt++) {
        f32x4 p;
        for (int r = 0; r < 4; r++) p[r] = fexp2(s[nt][r]);
        ps += p;
        pb[nt * 2]     = pk_bf16(p[0], p[1]);
        pb[nt * 2 + 1] = pk_bf16(p[2], p[3]);
      }
      lacc += ps;
    }

    for (int dt = 0; dt < 4; dt++) {
      uint4 vb0 = *(const uint4*)(V_ + (dt * 16 + col) * 64 + vg0);
      uint4 vb1 = *(const uint4*)(V_ + (dt * 16 + col) * 64 + (vg0 ^ 8));
      short4v vf[4];
      vf[0] = __builtin_bit_cast(short4v, (u32x2){vb0.x, vb0.y});
      vf[1] = __builtin_bit_cast(short4v, (u32x2){vb0.z, vb0.w});
      vf[2] = __builtin_bit_cast(short4v, (u32x2){vb1.x, vb1.y});
      vf[3] = __builtin_bit_cast(short4v, (u32x2){vb1.z, vb1.w});
      for (int nt = 0; nt < 4; nt++) {
        short4v pf = __builtin_bit_cast(short4v, (u32x2){pb[nt * 2], pb[nt * 2 + 1]});
        Oacc[dt] = mfma16(vf[nt], pf, Oacc[dt]);
      }
    }
  }

  {
    float l = (lacc[0] + lacc[1]) + (lacc[2] + lacc[3]);
    l += __shfl_xor(l, 16, 64);
    l += __shfl_xor(l, 32, 64);
    float rl = 1.0f / l;
    int q = qi * 64 + wave * 16 + col;
    u16* op = o + (size_t)(b * 2048 + q) * 1024 + h * 64;
    for (int dt = 0; dt < 4; dt++) {
      u16 ob[4] __attribute__((aligned(8)));
      for (int r = 0; r < 4; r++) ob[r] = f2bf(Oacc[dt][r] * rl);
      *(uint2*)(op + dt * 16 + quad * 4) = *(const uint2*)ob;
    }
  }
}

extern "C" void kernel_launch(void* const* d_in, const int* in_sizes, int n_in,
                              void* d_out, int out_size, void* d_ws, size_t ws_size,
                              hipStream_t stream) {
  const float* x      = (const float*)d_in[0];  // [B,T,C]
  const float* w_qkv  = (const float*)d_in[1];  // [C, 3C]
  const float* w_proj = (const float*)d_in[2];  // [C, C]
  float* out = (float*)d_out;

  u16* x_bf    = (u16*)d_ws;                    // 8192*1024
  u16* wqkvT   = x_bf + (size_t)8192 * 1024;    // 3072*1024
  u16* wprojT  = wqkvT + (size_t)3072 * 1024;   // 1024*1024
  u16* qk_buf  = wprojT + (size_t)1024 * 1024;  // 8192*2048  (Qscaled | K)
  u16* vt_perm = qk_buf + (size_t)8192 * 2048;  // 64*64*2048
  u16* attn_bf = vt_perm + (size_t)64 * 64 * 2048;  // 8192*1024

  const float qscale = 0.125f * 1.44269504f;    // 1/sqrt(64) * log2(e)

  prep<<<8192, 256, 0, stream>>>(x, w_qkv, w_proj, x_bf, wqkvT, wprojT);

  gemm_qkv<<<dim3(64, 24), 256, 0, stream>>>(x_bf, wqkvT, qk_buf, vt_perm, qscale);

  attn_fused<<<2048, 256, 0, stream>>>(qk_buf, vt_perm, attn_bf);

  gemm_proj<<<dim3(64, 8), 256, 0, stream>>>(attn_bf, wprojT, out, 8192, 1024, 1024);
}